// Round 13
// baseline (225.559 us; speedup 1.0000x reference)
//
#include <hip/hip_runtime.h>

#define Bn 8
#define Tn 4096
#define Dn 256
#define Mn (Bn*Tn)           // 32768

typedef short bf16x8 __attribute__((ext_vector_type(8)));
typedef float f32x4 __attribute__((ext_vector_type(4)));
typedef float f32x16 __attribute__((ext_vector_type(16)));

// ---- ws layout (bytes) ----
// phase A: wt @16 MB (384 KB)
// phase B: partials bf16 @0 (40 MB = 640 slots * 64 KB), ml float2 @41943040 (640 KB)
// persistent: qkv (Q, K, V^T bf16) @42598400 (48 MB)
#define P_OFF   0ul
#define ML_OFF  41943040ul
#define WT_OFF  16777216ul
#define QKV_OFF 42598400ul

__device__ __forceinline__ unsigned short f2bf(float f) {
    union { float f; unsigned int u; } v; v.f = f;
    unsigned int r = v.u + 0x7fffu + ((v.u >> 16) & 1u);
    return (unsigned short)(r >> 16);
}
__device__ __forceinline__ float bf2f(unsigned short u) {
    union { unsigned int u; float f; } v; v.u = ((unsigned int)u) << 16;
    return v.f;
}
// single-instruction packed f32x2 -> bf16x2 (RNE, same as f2bf)
__device__ __forceinline__ unsigned int cvtpk(float a, float b) {
    unsigned int r;
    asm("v_cvt_pk_bf16_f32 %0, %1, %2" : "=v"(r) : "v"(a), "v"(b));
    return r;
}

typedef __attribute__((address_space(1))) const unsigned int* gas_p;
typedef __attribute__((address_space(3))) unsigned int* las_p;
__device__ __forceinline__ void g2lds16(const void* g, void* l) {
    __builtin_amdgcn_global_load_lds((gas_p)g, (las_p)l, 16, 0, 0);
}

// ---------------- W transpose+cast ----------------
__global__ void __launch_bounds__(256) wt_kernel(const float* __restrict__ wq,
                                                 const float* __restrict__ wk,
                                                 const float* __restrict__ wv,
                                                 unsigned short* __restrict__ wt) {
    int idx = blockIdx.x * 256 + threadIdx.x;
    int h = idx >> 16; int r = idx & 65535;
    int k = r >> 8, n = r & 255;
    const float* src = (h == 0) ? wq : (h == 1) ? wk : wv;
    wt[h * 65536 + n * 256 + k] = f2bf(src[k * 256 + n]);
}

// ---------------- fused QKV projection: x staged ONCE per block ----------------
__global__ void __launch_bounds__(256, 2) proj_kernel(const float* __restrict__ x,
                                                      const unsigned short* __restrict__ wt,
                                                      unsigned short* __restrict__ qkv) {
    __shared__ unsigned short xlds[64 * 258];
    __shared__ unsigned short wlds[256 * 40];
    int m0 = blockIdx.x * 64;
    int tid = threadIdx.x;
    int w = tid >> 6, lane = tid & 63;
    int c = lane & 15, g = lane >> 4;

#pragma unroll
    for (int it = 0; it < 16; it++) {
        int idx = it * 256 + tid;          // f32x4 index
        int row = idx >> 6, col4 = (idx & 63) * 4;
        float4 a = *(const float4*)(x + (size_t)(m0 + row) * Dn + col4);
        union { unsigned short u[4]; ushort4 v4; } o4;
        o4.u[0] = f2bf(a.x); o4.u[1] = f2bf(a.y); o4.u[2] = f2bf(a.z); o4.u[3] = f2bf(a.w);
        *(ushort4*)(&xlds[row * 258 + col4]) = o4.v4;
    }
    __syncthreads();

    const f32x4 fz = {0.f, 0.f, 0.f, 0.f};
    for (int h = 0; h < 3; h++) {
        const unsigned short* wth = wt + h * 65536;
        f32x4 acc[16];
#pragma unroll
        for (int n = 0; n < 16; n++) acc[n] = fz;

        for (int kk = 0; kk < 8; kk++) {
            __syncthreads();
#pragma unroll
            for (int p = 0; p < 4; p++) {
                int idx = p * 256 + tid;
                int r = idx >> 2, ch = idx & 3;
                bf16x8 v = *(const bf16x8*)(wth + r * 256 + kk * 32 + ch * 8);
                *(bf16x8*)(&wlds[r * 40 + ch * 8]) = v;
            }
            __syncthreads();
            bf16x8 af = *(const bf16x8*)(&xlds[(w * 16 + c) * 258 + kk * 32 + g * 8]);
#pragma unroll
            for (int n = 0; n < 16; n++) {
                bf16x8 bfv = *(const bf16x8*)(&wlds[(n * 16 + c) * 40 + g * 8]);
                acc[n] = __builtin_amdgcn_mfma_f32_16x16x32_bf16(af, bfv, acc[n], 0, 0, 0);
            }
        }
        int orow0 = m0 + w * 16 + g * 4;
        if (h < 2) {
            unsigned short* out = qkv + (size_t)h * Mn * Dn;
#pragma unroll
            for (int n = 0; n < 16; n++)
#pragma unroll
                for (int r = 0; r < 4; r++)
                    out[(size_t)(orow0 + r) * Dn + n * 16 + c] = f2bf(acc[n][r]);
        } else {
            unsigned short* vt = qkv + (size_t)2 * Mn * Dn;   // [256][M]
#pragma unroll
            for (int n = 0; n < 16; n++) {
                union { unsigned short u[4]; ushort4 v4; } pk;
#pragma unroll
                for (int r = 0; r < 4; r++) pk.u[r] = f2bf(acc[n][r]);
                *(ushort4*)(vt + (size_t)(n * 16 + c) * Mn + orow0) = pk.v4;
            }
        }
    }
}

// ---------------- attention: round-11 base + isolated QK 2-chain split ----------------
__global__ void __launch_bounds__(256, 2) attn_kernel(const unsigned short* __restrict__ qkv,
                                                      unsigned short* __restrict__ part,
                                                      float2* __restrict__ ml) {
    __shared__ char smem[65536];   // 2 bufs x (K 16KB + V^T 16KB)

    int bid = blockIdx.x;
    int b = bid & 7;
    int r = bid >> 3;
    int qtp, cc;
    if (r < 24)      { qtp = 24 + (r & 7); cc = r >> 3; }
    else if (r < 40) { int rp = r - 24; qtp = 16 + (rp & 7); cc = rp >> 3; }
    else if (r < 48) { qtp = 8 + (r - 40); cc = 0; }
    else             { int k = r - 48; int u = k >> 2, v = k & 3; qtp = 8 * v + 7 - u; cc = v; }
    int slot = b * 80 + r;

    int tid = threadIdx.x, w = tid >> 6, lane = tid & 63;
    int lq = lane & 31, hh = lane >> 5;

    const unsigned short* Qg = qkv;
    const unsigned short* Kg = qkv + (size_t)Mn * Dn;
    const unsigned short* Vt = qkv + (size_t)2 * Mn * Dn;

    int qrow = qtp * 128 + w * 32 + lq;

    bf16x8 qf[16];
#pragma unroll
    for (int s = 0; s < 16; s++)
        qf[s] = *(const bf16x8*)(Qg + ((size_t)b * Tn + qrow) * Dn + s * 16 + hh * 8);

    f32x16 o[8];
#pragma unroll
    for (int dg = 0; dg < 8; dg++)
#pragma unroll
        for (int e = 0; e < 16; e++) o[dg][e] = 0.f;
    float m2 = -INFINITY, lsum = 0.f;

    const float C1 = 0.09016844005555897f;       // (1/16) * log2(e)

    auto STAGE = [&](int bufsel, int t) {
        const unsigned short* kgb = Kg + ((size_t)b * Tn + t * 32) * Dn;
        char* kb = smem + bufsel * 32768 + w * 4096;
#pragma unroll
        for (int i = 0; i < 4; i++) {
            int row = w * 8 + i * 2 + hh;
            int chunk = lq ^ row;
            g2lds16(kgb + row * 256 + chunk * 8, kb + i * 1024);
        }
        const unsigned short* vgb = Vt + (size_t)b * Tn + t * 32;
        char* vb = smem + bufsel * 32768 + 16384 + w * 4096;
#pragma unroll
        for (int i = 0; i < 4; i++) {
            int d = w * 64 + i * 16 + (lane >> 2);
            int kvc = (lane & 3) ^ ((d >> 3) & 3);
            g2lds16(vgb + (size_t)d * Mn + kvc * 8, vb + i * 1024);
        }
    };

    auto COMPUTE = [&](int bufsel, int t) {
        int kv0 = t * 32;
        const char* klds = smem + bufsel * 32768;
        const char* vlds = klds + 16384;
        // ---- S^T = K Q^T: two independent 8-chains (ONLY change vs round 11) ----
        f32x16 sva, svb;
#pragma unroll
        for (int e = 0; e < 16; e++) { sva[e] = 0.f; svb[e] = 0.f; }
        __builtin_amdgcn_s_setprio(1);
#pragma unroll
        for (int s = 0; s < 8; s++) {
            bf16x8 kfa = *(const bf16x8*)(klds + lq * 512 + ((2 * s + hh) ^ lq) * 16);
            sva = __builtin_amdgcn_mfma_f32_32x32x16_bf16(kfa, qf[s], sva, 0, 0, 0);
            bf16x8 kfb = *(const bf16x8*)(klds + lq * 512 + ((2 * (s + 8) + hh) ^ lq) * 16);
            svb = __builtin_amdgcn_mfma_f32_32x32x16_bf16(kfb, qf[s + 8], svb, 0, 0, 0);
        }
        __builtin_amdgcn_s_setprio(0);
        f32x16 sv = sva + svb;
        // ---- mask + scale ----
        float pv[16];
#pragma unroll
        for (int rr = 0; rr < 16; rr++) {
            int kvl = kv0 + (rr & 3) + 8 * (rr >> 2) + 4 * hh;
            float v = sv[rr] * C1;
            pv[rr] = (kvl <= qrow) ? v : -INFINITY;
        }
        // ---- max: pairwise tree (depth 4) ----
        float a8[8];
#pragma unroll
        for (int i = 0; i < 8; i++) a8[i] = fmaxf(pv[2 * i], pv[2 * i + 1]);
        float a4[4];
#pragma unroll
        for (int i = 0; i < 4; i++) a4[i] = fmaxf(a8[2 * i], a8[2 * i + 1]);
        float tmax = fmaxf(fmaxf(a4[0], a4[1]), fmaxf(a4[2], a4[3]));
        tmax = fmaxf(tmax, __shfl_xor(tmax, 32));
        float mn = m2;
        if (!__all(tmax - m2 <= 8.0f)) {          // T13 defer-max
            mn = fmaxf(m2, tmax);
            float alpha = exp2f(m2 - mn);
            lsum *= alpha;
            m2 = mn;
#pragma unroll
            for (int dg = 0; dg < 8; dg++) o[dg] = o[dg] * alpha;
        }
#pragma unroll
        for (int rr = 0; rr < 16; rr++) pv[rr] = exp2f(pv[rr] - mn);
        // ---- sum: pairwise tree ----
        float s8[8];
#pragma unroll
        for (int i = 0; i < 8; i++) s8[i] = pv[2 * i] + pv[2 * i + 1];
        float s4[4];
#pragma unroll
        for (int i = 0; i < 4; i++) s4[i] = s8[2 * i] + s8[2 * i + 1];
        float ps = (s4[0] + s4[1]) + (s4[2] + s4[3]);
        ps += __shfl_xor(ps, 32);
        lsum += ps;
        // ---- P^T B-fragments (cvt_pk pack + verified shfl_xor exchange) ----
        union U4 { unsigned int u[4]; bf16x8 v; };
        U4 fr[2];
#pragma unroll
        for (int s2 = 0; s2 < 2; s2++) {
            int bidx = 8 * s2;
            unsigned int w0 = cvtpk(pv[bidx + 0], pv[bidx + 1]);
            unsigned int w1 = cvtpk(pv[bidx + 2], pv[bidx + 3]);
            unsigned int y0 = cvtpk(pv[bidx + 4], pv[bidx + 5]);
            unsigned int y1 = cvtpk(pv[bidx + 6], pv[bidx + 7]);
            unsigned int e0 = hh ? w0 : y0;
            unsigned int e1 = hh ? w1 : y1;
            unsigned int x0 = (unsigned int)__shfl_xor((int)e0, 32);
            unsigned int x1 = (unsigned int)__shfl_xor((int)e1, 32);
            fr[s2].u[0] = hh ? x0 : w0;
            fr[s2].u[1] = hh ? x1 : w1;
            fr[s2].u[2] = hh ? y0 : x0;
            fr[s2].u[3] = hh ? y1 : x1;
        }
        __builtin_amdgcn_s_setprio(1);
#pragma unroll
        for (int dg = 0; dg < 8; dg++) {
            int d = 32 * dg + lq;
            int swz = (d >> 3) & 3;
#pragma unroll
            for (int s2 = 0; s2 < 2; s2++) {
                bf16x8 vf = *(const bf16x8*)(vlds + d * 64 + ((2 * s2 + hh) ^ swz) * 16);
                o[dg] = __builtin_amdgcn_mfma_f32_32x32x16_bf16(vf, fr[s2].v, o[dg], 0, 0, 0);
            }
        }
        __builtin_amdgcn_s_setprio(0);
    };

    int t0 = cc * 32;
    int tend = min(t0 + 32, 4 * (qtp + 1));
    int cur = 0;
    STAGE(0, t0);
    __syncthreads();
    for (int t = t0; t < tend; t++) {
        if (t + 1 < tend) STAGE(cur ^ 1, t + 1);
        COMPUTE(cur, t);
        __syncthreads();
        cur ^= 1;
    }

    if (hh == 0)
        ml[(size_t)slot * 128 + w * 32 + lq] = make_float2(m2, lsum);

    uint4* pb = (uint4*)part;
#pragma unroll
    for (int dg = 0; dg < 8; dg++) {
        uint4 lo, hi2;
        lo.x = cvtpk(o[dg][0], o[dg][1]);  lo.y = cvtpk(o[dg][2], o[dg][3]);
        lo.z = cvtpk(o[dg][4], o[dg][5]);  lo.w = cvtpk(o[dg][6], o[dg][7]);
        hi2.x = cvtpk(o[dg][8], o[dg][9]);  hi2.y = cvtpk(o[dg][10], o[dg][11]);
        hi2.z = cvtpk(o[dg][12], o[dg][13]); hi2.w = cvtpk(o[dg][14], o[dg][15]);
        size_t base = (size_t)slot * 4096 + w * 1024 + dg * 128 + lane;
        pb[base] = lo;
        pb[base + 64] = hi2;
    }
}

// ---------------- combine (round-5-verified) ----------------
__global__ void __launch_bounds__(256) combine_kernel(const unsigned short* __restrict__ part,
                                                      const float2* __restrict__ ml,
                                                      float* __restrict__ out) {
    __shared__ float2 mls[4][32];
    int bid = blockIdx.x;
    int b = bid & 7;
    int rest = bid >> 3;
    int qtp = rest >> 2, w = rest & 3;
    int nch = (qtp >> 3) + 1;
    int tid = threadIdx.x;

    int slots[4];
#pragma unroll
    for (int ci = 0; ci < 4; ci++) {
        int rr;
        if (ci == nch - 1)       rr = 48 + 4 * (7 - (qtp & 7)) + (qtp >> 3);
        else if (qtp >= 24)      rr = 8 * ci + (qtp - 24);
        else if (qtp >= 16)      rr = 24 + 8 * ci + (qtp - 16);
        else                     rr = 40 + (qtp - 8);
        slots[ci] = b * 80 + rr;
    }
    if (tid < nch * 32) {
        int ci = tid >> 5, qq = tid & 31;
        mls[ci][qq] = ml[(size_t)slots[ci] * 128 + w * 32 + qq];
    }
    __syncthreads();

    int dg = tid >> 5, h2 = (tid >> 4) & 1, ls = tid & 15;
    const uint4* pb = (const uint4*)part;

    for (int rd = 0; rd < 4; rd++) {
        int lane_idx = ls + 16 * rd;
        int q = lane_idx & 31, hh = lane_idx >> 5;
        float M = -INFINITY;
#pragma unroll
        for (int ci = 0; ci < 4; ci++)
            if (ci < nch) M = fmaxf(M, mls[ci][q].x);
        float L = 0.f, wgt[4];
#pragma unroll
        for (int ci = 0; ci < 4; ci++) {
            if (ci < nch) { wgt[ci] = exp2f(mls[ci][q].x - M); L += wgt[ci] * mls[ci][q].y; }
            else wgt[ci] = 0.f;
        }
        float inv = 1.f / L;
        float a[8];
#pragma unroll
        for (int e = 0; e < 8; e++) a[e] = 0.f;
#pragma unroll
        for (int ci = 0; ci < 4; ci++) {
            if (ci >= nch) break;
            uint4 u = pb[(size_t)slots[ci] * 4096 + w * 1024 + dg * 128 + h2 * 64 + lane_idx];
            float wg = wgt[ci];
            a[0] += wg * bf2f((unsigned short)(u.x & 0xffff));
            a[1] += wg * bf2f((unsigned short)(u.x >> 16));
            a[2] += wg * bf2f((unsigned short)(u.y & 0xffff));
            a[3] += wg * bf2f((unsigned short)(u.y >> 16));
            a[4] += wg * bf2f((unsigned short)(u.z & 0xffff));
            a[5] += wg * bf2f((unsigned short)(u.z >> 16));
            a[6] += wg * bf2f((unsigned short)(u.w & 0xffff));
            a[7] += wg * bf2f((unsigned short)(u.w >> 16));
        }
        size_t row = (size_t)b * Tn + qtp * 128 + w * 32 + q;
        int dbase = 32 * dg + 16 * h2 + 4 * hh;
        float4 A = {a[0] * inv, a[1] * inv, a[2] * inv, a[3] * inv};
        float4 Bv = {a[4] * inv, a[5] * inv, a[6] * inv, a[7] * inv};
        *(float4*)(out + row * 256 + dbase) = A;
        *(float4*)(out + row * 256 + dbase + 8) = Bv;
    }
}

extern "C" void kernel_launch(void* const* d_in, const int* in_sizes, int n_in,
                              void* d_out, int out_size, void* d_ws, size_t ws_size,
                              hipStream_t stream) {
    (void)in_sizes; (void)n_in; (void)out_size; (void)ws_size;
    const float* x  = (const float*)d_in[0];
    const float* wk = (const float*)d_in[1];
    const float* wq = (const float*)d_in[2];
    const float* wv = (const float*)d_in[3];
    float* outp = (float*)d_out;

    char* ws = (char*)d_ws;
    unsigned short* wt   = (unsigned short*)(ws + WT_OFF);
    unsigned short* qkv  = (unsigned short*)(ws + QKV_OFF);
    unsigned short* part = (unsigned short*)(ws + P_OFF);
    float2*         mlp  = (float2*)(ws + ML_OFF);

    wt_kernel<<<3 * 65536 / 256, 256, 0, stream>>>(wq, wk, wv, wt);
    proj_kernel<<<Mn / 64, 256, 0, stream>>>(x, wt, qkv);
    attn_kernel<<<640, 256, 0, stream>>>(qkv, part, mlp);
    combine_kernel<<<1024, 256, 0, stream>>>(part, mlp, outp);
}

// Round 14
// 201.834 us; speedup vs baseline: 1.1175x; 1.1175x over previous
//
#include <hip/hip_runtime.h>

#define Bn 8
#define Tn 4096
#define Dn 256
#define Mn (Bn*Tn)           // 32768

typedef short bf16x8 __attribute__((ext_vector_type(8)));
typedef float f32x4 __attribute__((ext_vector_type(4)));
typedef float f32x16 __attribute__((ext_vector_type(16)));

// ---- ws layout (bytes) ----
// phase A: wt @16 MB (384 KB)
// phase B: partials bf16 @0 (40 MB = 640 slots * 64 KB), ml float2 @41943040 (640 KB)
// persistent: qkv (Q, K, V^T bf16) @42598400 (48 MB)
#define P_OFF   0ul
#define ML_OFF  41943040ul
#define WT_OFF  16777216ul
#define QKV_OFF 42598400ul

__device__ __forceinline__ unsigned short f2bf(float f) {
    union { float f; unsigned int u; } v; v.f = f;
    unsigned int r = v.u + 0x7fffu + ((v.u >> 16) & 1u);
    return (unsigned short)(r >> 16);
}
__device__ __forceinline__ float bf2f(unsigned short u) {
    union { unsigned int u; float f; } v; v.u = ((unsigned int)u) << 16;
    return v.f;
}
// single-instruction packed f32x2 -> bf16x2 (RNE, same as f2bf)
__device__ __forceinline__ unsigned int cvtpk(float a, float b) {
    unsigned int r;
    asm("v_cvt_pk_bf16_f32 %0, %1, %2" : "=v"(r) : "v"(a), "v"(b));
    return r;
}

typedef __attribute__((address_space(1))) const unsigned int* gas_p;
typedef __attribute__((address_space(3))) unsigned int* las_p;
__device__ __forceinline__ void g2lds16(const void* g, void* l) {
    __builtin_amdgcn_global_load_lds((gas_p)g, (las_p)l, 16, 0, 0);
}

// ---------------- W transpose+cast ----------------
__global__ void __launch_bounds__(256) wt_kernel(const float* __restrict__ wq,
                                                 const float* __restrict__ wk,
                                                 const float* __restrict__ wv,
                                                 unsigned short* __restrict__ wt) {
    int idx = blockIdx.x * 256 + threadIdx.x;
    int h = idx >> 16; int r = idx & 65535;
    int k = r >> 8, n = r & 255;
    const float* src = (h == 0) ? wq : (h == 1) ? wk : wv;
    wt[h * 65536 + n * 256 + k] = f2bf(src[k * 256 + n]);
}

// ---------------- fused QKV projection: x staged ONCE per block ----------------
__global__ void __launch_bounds__(256, 2) proj_kernel(const float* __restrict__ x,
                                                      const unsigned short* __restrict__ wt,
                                                      unsigned short* __restrict__ qkv) {
    __shared__ unsigned short xlds[64 * 258];
    __shared__ unsigned short wlds[256 * 40];
    int m0 = blockIdx.x * 64;
    int tid = threadIdx.x;
    int w = tid >> 6, lane = tid & 63;
    int c = lane & 15, g = lane >> 4;

#pragma unroll
    for (int it = 0; it < 16; it++) {
        int idx = it * 256 + tid;          // f32x4 index
        int row = idx >> 6, col4 = (idx & 63) * 4;
        float4 a = *(const float4*)(x + (size_t)(m0 + row) * Dn + col4);
        union { unsigned short u[4]; ushort4 v4; } o4;
        o4.u[0] = f2bf(a.x); o4.u[1] = f2bf(a.y); o4.u[2] = f2bf(a.z); o4.u[3] = f2bf(a.w);
        *(ushort4*)(&xlds[row * 258 + col4]) = o4.v4;
    }
    __syncthreads();

    const f32x4 fz = {0.f, 0.f, 0.f, 0.f};
    for (int h = 0; h < 3; h++) {
        const unsigned short* wth = wt + h * 65536;
        f32x4 acc[16];
#pragma unroll
        for (int n = 0; n < 16; n++) acc[n] = fz;

        for (int kk = 0; kk < 8; kk++) {
            __syncthreads();
#pragma unroll
            for (int p = 0; p < 4; p++) {
                int idx = p * 256 + tid;
                int r = idx >> 2, ch = idx & 3;
                bf16x8 v = *(const bf16x8*)(wth + r * 256 + kk * 32 + ch * 8);
                *(bf16x8*)(&wlds[r * 40 + ch * 8]) = v;
            }
            __syncthreads();
            bf16x8 af = *(const bf16x8*)(&xlds[(w * 16 + c) * 258 + kk * 32 + g * 8]);
#pragma unroll
            for (int n = 0; n < 16; n++) {
                bf16x8 bfv = *(const bf16x8*)(&wlds[(n * 16 + c) * 40 + g * 8]);
                acc[n] = __builtin_amdgcn_mfma_f32_16x16x32_bf16(af, bfv, acc[n], 0, 0, 0);
            }
        }
        int orow0 = m0 + w * 16 + g * 4;
        if (h < 2) {
            unsigned short* out = qkv + (size_t)h * Mn * Dn;
#pragma unroll
            for (int n = 0; n < 16; n++)
#pragma unroll
                for (int r = 0; r < 4; r++)
                    out[(size_t)(orow0 + r) * Dn + n * 16 + c] = f2bf(acc[n][r]);
        } else {
            unsigned short* vt = qkv + (size_t)2 * Mn * Dn;   // [256][M]
#pragma unroll
            for (int n = 0; n < 16; n++) {
                union { unsigned short u[4]; ushort4 v4; } pk;
#pragma unroll
                for (int r = 0; r < 4; r++) pk.u[r] = f2bf(acc[n][r]);
                *(ushort4*)(vt + (size_t)(n * 16 + c) * Mn + orow0) = pk.v4;
            }
        }
    }
}

// ---------------- attention: round-11 verbatim loop; nch==1 blocks write out directly ----------------
__global__ void __launch_bounds__(256, 2) attn_kernel(const unsigned short* __restrict__ qkv,
                                                      unsigned short* __restrict__ part,
                                                      float2* __restrict__ ml,
                                                      float* __restrict__ outp) {
    __shared__ char smem[65536];   // 2 bufs x (K 16KB + V^T 16KB)

    int bid = blockIdx.x;
    int b = bid & 7;
    int r = bid >> 3;
    int qtp, cc;
    if (r < 24)      { qtp = 24 + (r & 7); cc = r >> 3; }
    else if (r < 40) { int rp = r - 24; qtp = 16 + (rp & 7); cc = rp >> 3; }
    else if (r < 48) { qtp = 8 + (r - 40); cc = 0; }
    else             { int k = r - 48; int u = k >> 2, v = k & 3; qtp = 8 * v + 7 - u; cc = v; }
    int slot = b * 80 + r;

    int tid = threadIdx.x, w = tid >> 6, lane = tid & 63;
    int lq = lane & 31, hh = lane >> 5;

    const unsigned short* Qg = qkv;
    const unsigned short* Kg = qkv + (size_t)Mn * Dn;
    const unsigned short* Vt = qkv + (size_t)2 * Mn * Dn;

    int qrow = qtp * 128 + w * 32 + lq;

    bf16x8 qf[16];
#pragma unroll
    for (int s = 0; s < 16; s++)
        qf[s] = *(const bf16x8*)(Qg + ((size_t)b * Tn + qrow) * Dn + s * 16 + hh * 8);

    f32x16 o[8];
#pragma unroll
    for (int dg = 0; dg < 8; dg++)
#pragma unroll
        for (int e = 0; e < 16; e++) o[dg][e] = 0.f;
    float m2 = -INFINITY, lsum = 0.f;

    const float C1 = 0.09016844005555897f;       // (1/16) * log2(e)

    auto STAGE = [&](int bufsel, int t) {
        const unsigned short* kgb = Kg + ((size_t)b * Tn + t * 32) * Dn;
        char* kb = smem + bufsel * 32768 + w * 4096;
#pragma unroll
        for (int i = 0; i < 4; i++) {
            int row = w * 8 + i * 2 + hh;
            int chunk = lq ^ row;
            g2lds16(kgb + row * 256 + chunk * 8, kb + i * 1024);
        }
        const unsigned short* vgb = Vt + (size_t)b * Tn + t * 32;
        char* vb = smem + bufsel * 32768 + 16384 + w * 4096;
#pragma unroll
        for (int i = 0; i < 4; i++) {
            int d = w * 64 + i * 16 + (lane >> 2);
            int kvc = (lane & 3) ^ ((d >> 3) & 3);
            g2lds16(vgb + (size_t)d * Mn + kvc * 8, vb + i * 1024);
        }
    };

    auto COMPUTE = [&](int bufsel, int t) {
        int kv0 = t * 32;
        const char* klds = smem + bufsel * 32768;
        const char* vlds = klds + 16384;
        f32x16 sv;
#pragma unroll
        for (int e = 0; e < 16; e++) sv[e] = 0.f;
        __builtin_amdgcn_s_setprio(1);
#pragma unroll
        for (int s = 0; s < 16; s++) {
            bf16x8 kf = *(const bf16x8*)(klds + lq * 512 + ((2 * s + hh) ^ lq) * 16);
            sv = __builtin_amdgcn_mfma_f32_32x32x16_bf16(kf, qf[s], sv, 0, 0, 0);
        }
        __builtin_amdgcn_s_setprio(0);
        // ---- mask + scale ----
        float pv[16];
#pragma unroll
        for (int rr = 0; rr < 16; rr++) {
            int kvl = kv0 + (rr & 3) + 8 * (rr >> 2) + 4 * hh;
            float v = sv[rr] * C1;
            pv[rr] = (kvl <= qrow) ? v : -INFINITY;
        }
        // ---- max: pairwise tree (depth 4) ----
        float a8[8];
#pragma unroll
        for (int i = 0; i < 8; i++) a8[i] = fmaxf(pv[2 * i], pv[2 * i + 1]);
        float a4[4];
#pragma unroll
        for (int i = 0; i < 4; i++) a4[i] = fmaxf(a8[2 * i], a8[2 * i + 1]);
        float tmax = fmaxf(fmaxf(a4[0], a4[1]), fmaxf(a4[2], a4[3]));
        tmax = fmaxf(tmax, __shfl_xor(tmax, 32));
        float mn = m2;
        if (!__all(tmax - m2 <= 8.0f)) {          // T13 defer-max
            mn = fmaxf(m2, tmax);
            float alpha = exp2f(m2 - mn);
            lsum *= alpha;
            m2 = mn;
#pragma unroll
            for (int dg = 0; dg < 8; dg++) o[dg] = o[dg] * alpha;
        }
#pragma unroll
        for (int rr = 0; rr < 16; rr++) pv[rr] = exp2f(pv[rr] - mn);
        // ---- sum: pairwise tree ----
        float s8[8];
#pragma unroll
        for (int i = 0; i < 8; i++) s8[i] = pv[2 * i] + pv[2 * i + 1];
        float s4[4];
#pragma unroll
        for (int i = 0; i < 4; i++) s4[i] = s8[2 * i] + s8[2 * i + 1];
        float ps = (s4[0] + s4[1]) + (s4[2] + s4[3]);
        ps += __shfl_xor(ps, 32);
        lsum += ps;
        // ---- P^T B-fragments (cvt_pk pack + verified shfl_xor exchange) ----
        union U4 { unsigned int u[4]; bf16x8 v; };
        U4 fr[2];
#pragma unroll
        for (int s2 = 0; s2 < 2; s2++) {
            int bidx = 8 * s2;
            unsigned int w0 = cvtpk(pv[bidx + 0], pv[bidx + 1]);
            unsigned int w1 = cvtpk(pv[bidx + 2], pv[bidx + 3]);
            unsigned int y0 = cvtpk(pv[bidx + 4], pv[bidx + 5]);
            unsigned int y1 = cvtpk(pv[bidx + 6], pv[bidx + 7]);
            unsigned int e0 = hh ? w0 : y0;
            unsigned int e1 = hh ? w1 : y1;
            unsigned int x0 = (unsigned int)__shfl_xor((int)e0, 32);
            unsigned int x1 = (unsigned int)__shfl_xor((int)e1, 32);
            fr[s2].u[0] = hh ? x0 : w0;
            fr[s2].u[1] = hh ? x1 : w1;
            fr[s2].u[2] = hh ? y0 : x0;
            fr[s2].u[3] = hh ? y1 : x1;
        }
        __builtin_amdgcn_s_setprio(1);
#pragma unroll
        for (int dg = 0; dg < 8; dg++) {
            int d = 32 * dg + lq;
            int swz = (d >> 3) & 3;
#pragma unroll
            for (int s2 = 0; s2 < 2; s2++) {
                bf16x8 vf = *(const bf16x8*)(vlds + d * 64 + ((2 * s2 + hh) ^ swz) * 16);
                o[dg] = __builtin_amdgcn_mfma_f32_32x32x16_bf16(vf, fr[s2].v, o[dg], 0, 0, 0);
            }
        }
        __builtin_amdgcn_s_setprio(0);
    };

    int t0 = cc * 32;
    int tend = min(t0 + 32, 4 * (qtp + 1));
    int cur = 0;
    STAGE(0, t0);
    __syncthreads();
    for (int t = t0; t < tend; t++) {
        if (t + 1 < tend) STAGE(cur ^ 1, t + 1);
        COMPUTE(cur, t);
        __syncthreads();
        cur ^= 1;
    }

    if (qtp < 8) {
        // nch==1: this block saw the whole causal row range -> write final output directly.
        // Verified C/D layout: lane (lq,hh) holds q=qrow, d = 32*dg + (e&3) + 8*(e>>2) + 4*hh.
        float inv = 1.0f / lsum;
        float* og = outp + ((size_t)b * Tn + qrow) * 256;
#pragma unroll
        for (int dg = 0; dg < 8; dg++)
#pragma unroll
            for (int j2 = 0; j2 < 4; j2++) {
                f32x4 v4 = { o[dg][4 * j2 + 0] * inv, o[dg][4 * j2 + 1] * inv,
                             o[dg][4 * j2 + 2] * inv, o[dg][4 * j2 + 3] * inv };
                *(f32x4*)(og + 32 * dg + 8 * j2 + 4 * hh) = v4;
            }
    } else {
        if (hh == 0)
            ml[(size_t)slot * 128 + w * 32 + lq] = make_float2(m2, lsum);
        uint4* pb = (uint4*)part;
#pragma unroll
        for (int dg = 0; dg < 8; dg++) {
            uint4 lo, hi2;
            lo.x = cvtpk(o[dg][0], o[dg][1]);  lo.y = cvtpk(o[dg][2], o[dg][3]);
            lo.z = cvtpk(o[dg][4], o[dg][5]);  lo.w = cvtpk(o[dg][6], o[dg][7]);
            hi2.x = cvtpk(o[dg][8], o[dg][9]);  hi2.y = cvtpk(o[dg][10], o[dg][11]);
            hi2.z = cvtpk(o[dg][12], o[dg][13]); hi2.w = cvtpk(o[dg][14], o[dg][15]);
            size_t base = (size_t)slot * 4096 + w * 1024 + dg * 128 + lane;
            pb[base] = lo;
            pb[base + 64] = hi2;
        }
    }
}

// ---------------- combine: qtp >= 8 only (768 blocks) ----------------
__global__ void __launch_bounds__(256) combine_kernel(const unsigned short* __restrict__ part,
                                                      const float2* __restrict__ ml,
                                                      float* __restrict__ out) {
    __shared__ float2 mls[4][32];
    int bid = blockIdx.x;
    int b = bid & 7;
    int rest = bid >> 3;                  // 0..95
    int qtp = 8 + (rest >> 2), w = rest & 3;
    int nch = (qtp >> 3) + 1;
    int tid = threadIdx.x;

    int slots[4];
#pragma unroll
    for (int ci = 0; ci < 4; ci++) {
        int rr;
        if (ci == nch - 1)       rr = 48 + 4 * (7 - (qtp & 7)) + (qtp >> 3);
        else if (qtp >= 24)      rr = 8 * ci + (qtp - 24);
        else if (qtp >= 16)      rr = 24 + 8 * ci + (qtp - 16);
        else                     rr = 40 + (qtp - 8);
        slots[ci] = b * 80 + rr;
    }
    if (tid < nch * 32) {
        int ci = tid >> 5, qq = tid & 31;
        mls[ci][qq] = ml[(size_t)slots[ci] * 128 + w * 32 + qq];
    }
    __syncthreads();

    int dg = tid >> 5, h2 = (tid >> 4) & 1, ls = tid & 15;
    const uint4* pb = (const uint4*)part;

    for (int rd = 0; rd < 4; rd++) {
        int lane_idx = ls + 16 * rd;
        int q = lane_idx & 31, hh = lane_idx >> 5;
        float M = -INFINITY;
#pragma unroll
        for (int ci = 0; ci < 4; ci++)
            if (ci < nch) M = fmaxf(M, mls[ci][q].x);
        float L = 0.f, wgt[4];
#pragma unroll
        for (int ci = 0; ci < 4; ci++) {
            if (ci < nch) { wgt[ci] = exp2f(mls[ci][q].x - M); L += wgt[ci] * mls[ci][q].y; }
            else wgt[ci] = 0.f;
        }
        float inv = 1.f / L;
        float a[8];
#pragma unroll
        for (int e = 0; e < 8; e++) a[e] = 0.f;
#pragma unroll
        for (int ci = 0; ci < 4; ci++) {
            if (ci >= nch) break;
            uint4 u = pb[(size_t)slots[ci] * 4096 + w * 1024 + dg * 128 + h2 * 64 + lane_idx];
            float wg = wgt[ci];
            a[0] += wg * bf2f((unsigned short)(u.x & 0xffff));
            a[1] += wg * bf2f((unsigned short)(u.x >> 16));
            a[2] += wg * bf2f((unsigned short)(u.y & 0xffff));
            a[3] += wg * bf2f((unsigned short)(u.y >> 16));
            a[4] += wg * bf2f((unsigned short)(u.z & 0xffff));
            a[5] += wg * bf2f((unsigned short)(u.z >> 16));
            a[6] += wg * bf2f((unsigned short)(u.w & 0xffff));
            a[7] += wg * bf2f((unsigned short)(u.w >> 16));
        }
        size_t row = (size_t)b * Tn + qtp * 128 + w * 32 + q;
        int dbase = 32 * dg + 16 * h2 + 4 * hh;
        float4 A = {a[0] * inv, a[1] * inv, a[2] * inv, a[3] * inv};
        float4 Bv = {a[4] * inv, a[5] * inv, a[6] * inv, a[7] * inv};
        *(float4*)(out + row * 256 + dbase) = A;
        *(float4*)(out + row * 256 + dbase + 8) = Bv;
    }
}

extern "C" void kernel_launch(void* const* d_in, const int* in_sizes, int n_in,
                              void* d_out, int out_size, void* d_ws, size_t ws_size,
                              hipStream_t stream) {
    (void)in_sizes; (void)n_in; (void)out_size; (void)ws_size;
    const float* x  = (const float*)d_in[0];
    const float* wk = (const float*)d_in[1];
    const float* wq = (const float*)d_in[2];
    const float* wv = (const float*)d_in[3];
    float* outp = (float*)d_out;

    char* ws = (char*)d_ws;
    unsigned short* wt   = (unsigned short*)(ws + WT_OFF);
    unsigned short* qkv  = (unsigned short*)(ws + QKV_OFF);
    unsigned short* part = (unsigned short*)(ws + P_OFF);
    float2*         mlp  = (float2*)(ws + ML_OFF);

    wt_kernel<<<3 * 65536 / 256, 256, 0, stream>>>(wq, wk, wv, wt);
    proj_kernel<<<Mn / 64, 256, 0, stream>>>(x, wt, qkv);
    attn_kernel<<<640, 256, 0, stream>>>(qkv, part, mlp, outp);
    combine_kernel<<<768, 256, 0, stream>>>(part, mlp, outp);
}

// Round 15
// 194.985 us; speedup vs baseline: 1.1568x; 1.0351x over previous
//
#include <hip/hip_runtime.h>

#define Bn 8
#define Tn 4096
#define Dn 256
#define Mn (Bn*Tn)           // 32768

typedef short bf16x8 __attribute__((ext_vector_type(8)));
typedef float f32x4 __attribute__((ext_vector_type(4)));
typedef float f32x16 __attribute__((ext_vector_type(16)));

// ---- ws layout (bytes) ----
// phase A: wt @16 MB (384 KB)
// phase B: partials bf16 @0 (40 MB = 640 slots * 64 KB), ml float2 @41943040 (640 KB)
// persistent: qkv (Q, K, V^T bf16) @42598400 (48 MB)
#define P_OFF   0ul
#define ML_OFF  41943040ul
#define WT_OFF  16777216ul
#define QKV_OFF 42598400ul

__device__ __forceinline__ unsigned short f2bf(float f) {
    union { float f; unsigned int u; } v; v.f = f;
    unsigned int r = v.u + 0x7fffu + ((v.u >> 16) & 1u);
    return (unsigned short)(r >> 16);
}
__device__ __forceinline__ float bf2f(unsigned short u) {
    union { unsigned int u; float f; } v; v.u = ((unsigned int)u) << 16;
    return v.f;
}
// single-instruction packed f32x2 -> bf16x2 (RNE, same as f2bf)
__device__ __forceinline__ unsigned int cvtpk(float a, float b) {
    unsigned int r;
    asm("v_cvt_pk_bf16_f32 %0, %1, %2" : "=v"(r) : "v"(a), "v"(b));
    return r;
}

typedef __attribute__((address_space(1))) const unsigned int* gas_p;
typedef __attribute__((address_space(3))) unsigned int* las_p;
__device__ __forceinline__ void g2lds16(const void* g, void* l) {
    __builtin_amdgcn_global_load_lds((gas_p)g, (las_p)l, 16, 0, 0);
}

// ---------------- W transpose+cast ----------------
__global__ void __launch_bounds__(256) wt_kernel(const float* __restrict__ wq,
                                                 const float* __restrict__ wk,
                                                 const float* __restrict__ wv,
                                                 unsigned short* __restrict__ wt) {
    int idx = blockIdx.x * 256 + threadIdx.x;
    int h = idx >> 16; int r = idx & 65535;
    int k = r >> 8, n = r & 255;
    const float* src = (h == 0) ? wq : (h == 1) ? wk : wv;
    wt[h * 65536 + n * 256 + k] = f2bf(src[k * 256 + n]);
}

// ---------------- fused QKV projection: x staged ONCE per block ----------------
__global__ void __launch_bounds__(256, 2) proj_kernel(const float* __restrict__ x,
                                                      const unsigned short* __restrict__ wt,
                                                      unsigned short* __restrict__ qkv) {
    __shared__ unsigned short xlds[64 * 258];
    __shared__ unsigned short wlds[256 * 40];
    int m0 = blockIdx.x * 64;
    int tid = threadIdx.x;
    int w = tid >> 6, lane = tid & 63;
    int c = lane & 15, g = lane >> 4;

#pragma unroll
    for (int it = 0; it < 16; it++) {
        int idx = it * 256 + tid;          // f32x4 index
        int row = idx >> 6, col4 = (idx & 63) * 4;
        float4 a = *(const float4*)(x + (size_t)(m0 + row) * Dn + col4);
        union { unsigned short u[4]; ushort4 v4; } o4;
        o4.u[0] = f2bf(a.x); o4.u[1] = f2bf(a.y); o4.u[2] = f2bf(a.z); o4.u[3] = f2bf(a.w);
        *(ushort4*)(&xlds[row * 258 + col4]) = o4.v4;
    }
    __syncthreads();

    const f32x4 fz = {0.f, 0.f, 0.f, 0.f};
    for (int h = 0; h < 3; h++) {
        const unsigned short* wth = wt + h * 65536;
        f32x4 acc[16];
#pragma unroll
        for (int n = 0; n < 16; n++) acc[n] = fz;

        for (int kk = 0; kk < 8; kk++) {
            __syncthreads();
#pragma unroll
            for (int p = 0; p < 4; p++) {
                int idx = p * 256 + tid;
                int r = idx >> 2, ch = idx & 3;
                bf16x8 v = *(const bf16x8*)(wth + r * 256 + kk * 32 + ch * 8);
                *(bf16x8*)(&wlds[r * 40 + ch * 8]) = v;
            }
            __syncthreads();
            bf16x8 af = *(const bf16x8*)(&xlds[(w * 16 + c) * 258 + kk * 32 + g * 8]);
#pragma unroll
            for (int n = 0; n < 16; n++) {
                bf16x8 bfv = *(const bf16x8*)(&wlds[(n * 16 + c) * 40 + g * 8]);
                acc[n] = __builtin_amdgcn_mfma_f32_16x16x32_bf16(af, bfv, acc[n], 0, 0, 0);
            }
        }
        int orow0 = m0 + w * 16 + g * 4;
        if (h < 2) {
            unsigned short* out = qkv + (size_t)h * Mn * Dn;
#pragma unroll
            for (int n = 0; n < 16; n++)
#pragma unroll
                for (int r = 0; r < 4; r++)
                    out[(size_t)(orow0 + r) * Dn + n * 16 + c] = f2bf(acc[n][r]);
        } else {
            unsigned short* vt = qkv + (size_t)2 * Mn * Dn;   // [256][M]
#pragma unroll
            for (int n = 0; n < 16; n++) {
                union { unsigned short u[4]; ushort4 v4; } pk;
#pragma unroll
                for (int r = 0; r < 4; r++) pk.u[r] = f2bf(acc[n][r]);
                *(ushort4*)(vt + (size_t)(n * 16 + c) * Mn + orow0) = pk.v4;
            }
        }
    }
}

// ---------------- attention: round-11 verified optimum ----------------
__global__ void __launch_bounds__(256, 2) attn_kernel(const unsigned short* __restrict__ qkv,
                                                      unsigned short* __restrict__ part,
                                                      float2* __restrict__ ml) {
    __shared__ char smem[65536];   // 2 bufs x (K 16KB + V^T 16KB)

    int bid = blockIdx.x;
    int b = bid & 7;
    int r = bid >> 3;
    int qtp, cc;
    if (r < 24)      { qtp = 24 + (r & 7); cc = r >> 3; }
    else if (r < 40) { int rp = r - 24; qtp = 16 + (rp & 7); cc = rp >> 3; }
    else if (r < 48) { qtp = 8 + (r - 40); cc = 0; }
    else             { int k = r - 48; int u = k >> 2, v = k & 3; qtp = 8 * v + 7 - u; cc = v; }
    int slot = b * 80 + r;

    int tid = threadIdx.x, w = tid >> 6, lane = tid & 63;
    int lq = lane & 31, hh = lane >> 5;

    const unsigned short* Qg = qkv;
    const unsigned short* Kg = qkv + (size_t)Mn * Dn;
    const unsigned short* Vt = qkv + (size_t)2 * Mn * Dn;

    int qrow = qtp * 128 + w * 32 + lq;

    bf16x8 qf[16];
#pragma unroll
    for (int s = 0; s < 16; s++)
        qf[s] = *(const bf16x8*)(Qg + ((size_t)b * Tn + qrow) * Dn + s * 16 + hh * 8);

    f32x16 o[8];
#pragma unroll
    for (int dg = 0; dg < 8; dg++)
#pragma unroll
        for (int e = 0; e < 16; e++) o[dg][e] = 0.f;
    float m2 = -INFINITY, lsum = 0.f;

    const float C1 = 0.09016844005555897f;       // (1/16) * log2(e)

    auto STAGE = [&](int bufsel, int t) {
        const unsigned short* kgb = Kg + ((size_t)b * Tn + t * 32) * Dn;
        char* kb = smem + bufsel * 32768 + w * 4096;
#pragma unroll
        for (int i = 0; i < 4; i++) {
            int row = w * 8 + i * 2 + hh;
            int chunk = lq ^ row;
            g2lds16(kgb + row * 256 + chunk * 8, kb + i * 1024);
        }
        const unsigned short* vgb = Vt + (size_t)b * Tn + t * 32;
        char* vb = smem + bufsel * 32768 + 16384 + w * 4096;
#pragma unroll
        for (int i = 0; i < 4; i++) {
            int d = w * 64 + i * 16 + (lane >> 2);
            int kvc = (lane & 3) ^ ((d >> 3) & 3);
            g2lds16(vgb + (size_t)d * Mn + kvc * 8, vb + i * 1024);
        }
    };

    auto COMPUTE = [&](int bufsel, int t) {
        int kv0 = t * 32;
        const char* klds = smem + bufsel * 32768;
        const char* vlds = klds + 16384;
        f32x16 sv;
#pragma unroll
        for (int e = 0; e < 16; e++) sv[e] = 0.f;
        __builtin_amdgcn_s_setprio(1);
#pragma unroll
        for (int s = 0; s < 16; s++) {
            bf16x8 kf = *(const bf16x8*)(klds + lq * 512 + ((2 * s + hh) ^ lq) * 16);
            sv = __builtin_amdgcn_mfma_f32_32x32x16_bf16(kf, qf[s], sv, 0, 0, 0);
        }
        __builtin_amdgcn_s_setprio(0);
        // ---- mask + scale ----
        float pv[16];
#pragma unroll
        for (int rr = 0; rr < 16; rr++) {
            int kvl = kv0 + (rr & 3) + 8 * (rr >> 2) + 4 * hh;
            float v = sv[rr] * C1;
            pv[rr] = (kvl <= qrow) ? v : -INFINITY;
        }
        // ---- max: pairwise tree (depth 4) ----
        float a8[8];
#pragma unroll
        for (int i = 0; i < 8; i++) a8[i] = fmaxf(pv[2 * i], pv[2 * i + 1]);
        float a4[4];
#pragma unroll
        for (int i = 0; i < 4; i++) a4[i] = fmaxf(a8[2 * i], a8[2 * i + 1]);
        float tmax = fmaxf(fmaxf(a4[0], a4[1]), fmaxf(a4[2], a4[3]));
        tmax = fmaxf(tmax, __shfl_xor(tmax, 32));
        float mn = m2;
        if (!__all(tmax - m2 <= 8.0f)) {          // T13 defer-max
            mn = fmaxf(m2, tmax);
            float alpha = exp2f(m2 - mn);
            lsum *= alpha;
            m2 = mn;
#pragma unroll
            for (int dg = 0; dg < 8; dg++) o[dg] = o[dg] * alpha;
        }
#pragma unroll
        for (int rr = 0; rr < 16; rr++) pv[rr] = exp2f(pv[rr] - mn);
        // ---- sum: pairwise tree ----
        float s8[8];
#pragma unroll
        for (int i = 0; i < 8; i++) s8[i] = pv[2 * i] + pv[2 * i + 1];
        float s4[4];
#pragma unroll
        for (int i = 0; i < 4; i++) s4[i] = s8[2 * i] + s8[2 * i + 1];
        float ps = (s4[0] + s4[1]) + (s4[2] + s4[3]);
        ps += __shfl_xor(ps, 32);
        lsum += ps;
        // ---- P^T B-fragments (cvt_pk pack + verified shfl_xor exchange) ----
        union U4 { unsigned int u[4]; bf16x8 v; };
        U4 fr[2];
#pragma unroll
        for (int s2 = 0; s2 < 2; s2++) {
            int bidx = 8 * s2;
            unsigned int w0 = cvtpk(pv[bidx + 0], pv[bidx + 1]);
            unsigned int w1 = cvtpk(pv[bidx + 2], pv[bidx + 3]);
            unsigned int y0 = cvtpk(pv[bidx + 4], pv[bidx + 5]);
            unsigned int y1 = cvtpk(pv[bidx + 6], pv[bidx + 7]);
            unsigned int e0 = hh ? w0 : y0;
            unsigned int e1 = hh ? w1 : y1;
            unsigned int x0 = (unsigned int)__shfl_xor((int)e0, 32);
            unsigned int x1 = (unsigned int)__shfl_xor((int)e1, 32);
            fr[s2].u[0] = hh ? x0 : w0;
            fr[s2].u[1] = hh ? x1 : w1;
            fr[s2].u[2] = hh ? y0 : x0;
            fr[s2].u[3] = hh ? y1 : x1;
        }
        __builtin_amdgcn_s_setprio(1);
#pragma unroll
        for (int dg = 0; dg < 8; dg++) {
            int d = 32 * dg + lq;
            int swz = (d >> 3) & 3;
#pragma unroll
            for (int s2 = 0; s2 < 2; s2++) {
                bf16x8 vf = *(const bf16x8*)(vlds + d * 64 + ((2 * s2 + hh) ^ swz) * 16);
                o[dg] = __builtin_amdgcn_mfma_f32_32x32x16_bf16(vf, fr[s2].v, o[dg], 0, 0, 0);
            }
        }
        __builtin_amdgcn_s_setprio(0);
    };

    int t0 = cc * 32;
    int tend = min(t0 + 32, 4 * (qtp + 1));
    int cur = 0;
    STAGE(0, t0);
    __syncthreads();
    for (int t = t0; t < tend; t++) {
        if (t + 1 < tend) STAGE(cur ^ 1, t + 1);
        COMPUTE(cur, t);
        __syncthreads();
        cur ^= 1;
    }

    if (hh == 0)
        ml[(size_t)slot * 128 + w * 32 + lq] = make_float2(m2, lsum);

    uint4* pb = (uint4*)part;
#pragma unroll
    for (int dg = 0; dg < 8; dg++) {
        uint4 lo, hi2;
        lo.x = cvtpk(o[dg][0], o[dg][1]);  lo.y = cvtpk(o[dg][2], o[dg][3]);
        lo.z = cvtpk(o[dg][4], o[dg][5]);  lo.w = cvtpk(o[dg][6], o[dg][7]);
        hi2.x = cvtpk(o[dg][8], o[dg][9]);  hi2.y = cvtpk(o[dg][10], o[dg][11]);
        hi2.z = cvtpk(o[dg][12], o[dg][13]); hi2.w = cvtpk(o[dg][14], o[dg][15]);
        size_t base = (size_t)slot * 4096 + w * 1024 + dg * 128 + lane;
        pb[base] = lo;
        pb[base + 64] = hi2;
    }
}

// ---------------- combine (round-5-verified) ----------------
__global__ void __launch_bounds__(256) combine_kernel(const unsigned short* __restrict__ part,
                                                      const float2* __restrict__ ml,
                                                      float* __restrict__ out) {
    __shared__ float2 mls[4][32];
    int bid = blockIdx.x;
    int b = bid & 7;
    int rest = bid >> 3;
    int qtp = rest >> 2, w = rest & 3;
    int nch = (qtp >> 3) + 1;
    int tid = threadIdx.x;

    int slots[4];
#pragma unroll
    for (int ci = 0; ci < 4; ci++) {
        int rr;
        if (ci == nch - 1)       rr = 48 + 4 * (7 - (qtp & 7)) + (qtp >> 3);
        else if (qtp >= 24)      rr = 8 * ci + (qtp - 24);
        else if (qtp >= 16)      rr = 24 + 8 * ci + (qtp - 16);
        else                     rr = 40 + (qtp - 8);
        slots[ci] = b * 80 + rr;
    }
    if (tid < nch * 32) {
        int ci = tid >> 5, qq = tid & 31;
        mls[ci][qq] = ml[(size_t)slots[ci] * 128 + w * 32 + qq];
    }
    __syncthreads();

    int dg = tid >> 5, h2 = (tid >> 4) & 1, ls = tid & 15;
    const uint4* pb = (const uint4*)part;

    for (int rd = 0; rd < 4; rd++) {
        int lane_idx = ls + 16 * rd;
        int q = lane_idx & 31, hh = lane_idx >> 5;
        float M = -INFINITY;
#pragma unroll
        for (int ci = 0; ci < 4; ci++)
            if (ci < nch) M = fmaxf(M, mls[ci][q].x);
        float L = 0.f, wgt[4];
#pragma unroll
        for (int ci = 0; ci < 4; ci++) {
            if (ci < nch) { wgt[ci] = exp2f(mls[ci][q].x - M); L += wgt[ci] * mls[ci][q].y; }
            else wgt[ci] = 0.f;
        }
        float inv = 1.f / L;
        float a[8];
#pragma unroll
        for (int e = 0; e < 8; e++) a[e] = 0.f;
#pragma unroll
        for (int ci = 0; ci < 4; ci++) {
            if (ci >= nch) break;
            uint4 u = pb[(size_t)slots[ci] * 4096 + w * 1024 + dg * 128 + h2 * 64 + lane_idx];
            float wg = wgt[ci];
            a[0] += wg * bf2f((unsigned short)(u.x & 0xffff));
            a[1] += wg * bf2f((unsigned short)(u.x >> 16));
            a[2] += wg * bf2f((unsigned short)(u.y & 0xffff));
            a[3] += wg * bf2f((unsigned short)(u.y >> 16));
            a[4] += wg * bf2f((unsigned short)(u.z & 0xffff));
            a[5] += wg * bf2f((unsigned short)(u.z >> 16));
            a[6] += wg * bf2f((unsigned short)(u.w & 0xffff));
            a[7] += wg * bf2f((unsigned short)(u.w >> 16));
        }
        size_t row = (size_t)b * Tn + qtp * 128 + w * 32 + q;
        int dbase = 32 * dg + 16 * h2 + 4 * hh;
        float4 A = {a[0] * inv, a[1] * inv, a[2] * inv, a[3] * inv};
        float4 Bv = {a[4] * inv, a[5] * inv, a[6] * inv, a[7] * inv};
        *(float4*)(out + row * 256 + dbase) = A;
        *(float4*)(out + row * 256 + dbase + 8) = Bv;
    }
}

extern "C" void kernel_launch(void* const* d_in, const int* in_sizes, int n_in,
                              void* d_out, int out_size, void* d_ws, size_t ws_size,
                              hipStream_t stream) {
    (void)in_sizes; (void)n_in; (void)out_size; (void)ws_size;
    const float* x  = (const float*)d_in[0];
    const float* wk = (const float*)d_in[1];
    const float* wq = (const float*)d_in[2];
    const float* wv = (const float*)d_in[3];
    float* outp = (float*)d_out;

    char* ws = (char*)d_ws;
    unsigned short* wt   = (unsigned short*)(ws + WT_OFF);
    unsigned short* qkv  = (unsigned short*)(ws + QKV_OFF);
    unsigned short* part = (unsigned short*)(ws + P_OFF);
    float2*         mlp  = (float2*)(ws + ML_OFF);

    wt_kernel<<<3 * 65536 / 256, 256, 0, stream>>>(wq, wk, wv, wt);
    proj_kernel<<<Mn / 64, 256, 0, stream>>>(x, wt, qkv);
    attn_kernel<<<640, 256, 0, stream>>>(qkv, part, mlp);
    combine_kernel<<<1024, 256, 0, stream>>>(part, mlp, outp);
}